// Round 19
// baseline (114.733 us; speedup 1.0000x reference)
//
#include <hip/hip_runtime.h>
#include <hip/hip_bf16.h>

// B=8, DIM=256, HEADS=8, HD=32, WS=8, TOPK=4, H=W=64, gh=gw=8, R=64, T=64, BH=64.
#define ATT_SCALE 0.17677669529663687f
#define EXP_C1 0.2550349235534668f        // ATT_SCALE * log2(e)
#define EXP_C2 23.083120654223400f        // 16 * log2(e)

typedef short v8s __attribute__((ext_vector_type(8)));
typedef float v4f __attribute__((ext_vector_type(4)));
typedef float v16f __attribute__((ext_vector_type(16)));
typedef const __attribute__((address_space(1))) unsigned int gu32;
typedef __attribute__((address_space(3))) unsigned int lu32;

__device__ __forceinline__ void g2l16(const void* g, void* l) {
  __builtin_amdgcn_global_load_lds((gu32*)g, (lu32*)l, 16, 0, 0);
}

__device__ __forceinline__ float bflo(unsigned u){ union{unsigned i;float f;}x; x.i=u<<16; return x.f; }
__device__ __forceinline__ float bfhi(unsigned u){ union{unsigned i;float f;}x; x.i=u&0xffff0000u; return x.f; }
__device__ __forceinline__ unsigned short bf16r(float v){
  __hip_bfloat16 h = __float2bfloat16(v);
  return *reinterpret_cast<unsigned short*>(&h);
}
__device__ __forceinline__ unsigned pack_bf2(float a, float b){
  return (unsigned)bf16r(a) | ((unsigned)bf16r(b) << 16);
}
__device__ __forceinline__ unsigned cvtpk(float lo, float hi){
  unsigned r;
  asm("v_cvt_pk_bf16_f32 %0, %1, %2" : "=v"(r) : "v"(lo), "v"(hi));
  return r;
}
__device__ __forceinline__ void pl32swap(unsigned &a, unsigned &b){
  asm volatile("v_permlane32_swap_b32 %0, %1" : "+v"(a), "+v"(b));
}

// ---------------- W prep: fp32 -> bf16, K-swizzled -----------------------------
__global__ __launch_bounds__(256) void k_wprep(const float* __restrict__ w_qkv,
                                               const float* __restrict__ w_proj,
                                               unsigned short* __restrict__ Wq,
                                               unsigned short* __restrict__ Wp) {
  const int m = blockIdx.x, t = threadIdx.x;
  const float* src = (m < 768) ? (w_qkv + m*256) : (w_proj + (size_t)(m - 768)*256);
  unsigned short* dst = (m < 768) ? (Wq + m*256) : (Wp + (size_t)(m - 768)*256);
  int col = (t & ~63) | ((t & 63) ^ ((m & 7) << 3));   // (m-768)&7 == m&7
  dst[col] = bf16r(src[t]);
}

// ---------------- FUSED: x transpose->LDS + window partials + qkv MFMA GEMM ----
// Phase 1: ALL 64 x loads hoisted (single latency window). Phase 2: 24-stage
// pipeline, W TRIPLE-buffered, counted vmcnt + RAW s_barrier. v re-blocked
// [BH][R][t>>3][HD][t&7] (full-sector writes, round-18 win).
__global__ __launch_bounds__(256) void k_fqkv(
    const float* __restrict__ x,
    const unsigned short* __restrict__ Wq,
    const float* __restrict__ bias,
    unsigned short* __restrict__ qbuf, unsigned short* __restrict__ kbuf,
    unsigned short* __restrict__ vbuf, float* __restrict__ part) {
  __shared__ __align__(16) char lds[81920];  // [0,32K) X | 3 x 16K W bufs
  const int tid = threadIdx.x;
  const int wv = tid >> 6, lane = tid & 63;
  const int nt = blockIdx.x;
  const int b = nt >> 6, pc = nt & 63;
  const int p0 = pc << 6;
  float* pbuf = (float*)(lds + 65536);       // 8 KB overlay on W buf2 (dead until s=0)

  const char* wlanebase = (const char*)Wq + ((size_t)(lane >> 3))*512 + (lane & 7)*16;

  auto stage = [&](int s2, int buf) {
    const int m2 = s2 >> 2, kt2 = s2 & 3;
    char* dst = lds + 32768 + buf*16384;
    #pragma unroll
    for (int o = 0; o < 4; ++o) {
      int op = wv*4 + o;
      g2l16(wlanebase + (size_t)(m2*128 + op*8)*512 + kt2*128, dst + op*1024);
    }
  };

  // prologue W stages issued FIRST: their L2 latency hides under phase 1
  stage(0, 0);
  stage(1, 1);

  // ---- phase 1: transpose + partials (all 64 x loads issued up front)
  float hi[4][16];
  #pragma unroll
  for (int cc = 0; cc < 4; ++cc) {
    const float* xp = x + ((size_t)(b*256 + cc*64 + wv*16))*4096 + p0 + lane;
    #pragma unroll
    for (int i = 0; i < 16; ++i) hi[cc][i] = xp[(size_t)i*4096];
  }
  #pragma unroll
  for (int cc = 0; cc < 4; ++cc) {
    #pragma unroll
    for (int i = 0; i < 16; ++i) {
      float s = hi[cc][i];
      s += __shfl_xor(s, 1);
      s += __shfl_xor(s, 2);
      s += __shfl_xor(s, 4);
      if ((lane & 7) == 0) pbuf[cc*512 + (wv*16 + i)*8 + (lane >> 3)] = s;
    }
    #pragma unroll
    for (int gi = 0; gi < 2; ++gi) {
      uint4 uh;
      uh.x = pack_bf2(hi[cc][gi*8+0], hi[cc][gi*8+1]); uh.y = pack_bf2(hi[cc][gi*8+2], hi[cc][gi*8+3]);
      uh.z = pack_bf2(hi[cc][gi*8+4], hi[cc][gi*8+5]); uh.w = pack_bf2(hi[cc][gi*8+6], hi[cc][gi*8+7]);
      int off = lane*512 + cc*128 + ((wv*32 + gi*16) ^ ((lane & 7) << 4));
      *(uint4*)(lds + off) = uh;
    }
  }
  __syncthreads();
  {
    const size_t pbase = (size_t)(b*64 + pc)*2048;
    #pragma unroll
    for (int s = 0; s < 8; ++s) part[pbase + s*256 + tid] = pbuf[s*256 + tid];
  }
  __syncthreads();   // drains vmcnt -> prologue stages 0,1 landed; pbuf dead

  auto epilogue = [&](int mm, v4f (*acc)[4]) {
    if (mm < 4) {                             // q (mm 0,1) / k (mm 2,3)
      unsigned short* outbuf = (mm < 2) ? qbuf : kbuf;
      #pragma unroll
      for (int i = 0; i < 2; ++i) {
        int o = mm*128 + wv*32 + i*16 + ((lane >> 4) << 2);
        int head = (o >> 5) & 7, d0 = o & 31;
        float b0 = bias[o], b1 = bias[o+1], b2 = bias[o+2], b3 = bias[o+3];
        #pragma unroll
        for (int j = 0; j < 4; ++j) {
          int p = nt*64 + j*16 + (lane & 15);
          int bb = p >> 12, ploc = p & 4095;
          int h = ploc >> 6, w = ploc & 63;
          int rr = ((h >> 3) << 3) | (w >> 3), tt = ((h & 7) << 3) | (w & 7);
          int bh = bb*8 + head;
          uint2 u;
          u.x = pack_bf2(acc[i][j][0] + b0, acc[i][j][1] + b1);
          u.y = pack_bf2(acc[i][j][2] + b2, acc[i][j][3] + b3);
          *(uint2*)(outbuf + (size_t)(((bh << 6) | rr)*64 + tt)*32 + d0) = u;
        }
      }
    } else {              // v -> re-blocked [BH][R][t>>3][HD 32][t&7]
      #pragma unroll
      for (int i = 0; i < 2; ++i) {
        int o = mm*128 + wv*32 + i*16 + ((lane >> 4) << 2);
        int vch = o - 512;
        int head = vch >> 5, d0 = vch & 31;
        float bv[4] = {bias[o], bias[o+1], bias[o+2], bias[o+3]};
        #pragma unroll
        for (int j = 0; j < 4; ++j) {
          int p = nt*64 + j*16 + (lane & 15);
          int bb = p >> 12, ploc = p & 4095;
          int h = ploc >> 6, w = ploc & 63;
          int rr = ((h >> 3) << 3) | (w >> 3), tt = ((h & 7) << 3) | (w & 7);
          int bh = bb*8 + head;
          size_t base = ((size_t)(((bh << 6) | rr)*8 + (tt >> 3)))*256
                      + (size_t)d0*8 + (tt & 7);
          #pragma unroll
          for (int c = 0; c < 4; ++c)
            vbuf[base + (size_t)c*8] = bf16r(acc[i][j][c] + bv[c]);
        }
      }
    }
  };

  v4f accA[2][4], accB[2][4];

  #pragma unroll
  for (int s = 0; s < 24; ++s) {
    const int m = s >> 2, kt = s & 3, cur = s % 3;
    v4f (*acc)[4] = (m & 1) ? accB : accA;
    if (kt == 0) {
      #pragma unroll
      for (int i = 0; i < 2; ++i)
        #pragma unroll
        for (int j = 0; j < 4; ++j) acc[i][j] = (v4f){0.f,0.f,0.f,0.f};
    }
    if (s < 22) stage(s + 2, (s + 2) % 3);
    if (kt == 0 && m > 0) {
      __builtin_amdgcn_sched_barrier(0);      // keep stores AFTER the stage loads
      epilogue(m - 1, (m & 1) ? accA : accB);
      __builtin_amdgcn_sched_barrier(0);
    }
    {
      const char* wb = lds + 32768 + cur*16384;
      __builtin_amdgcn_s_setprio(1);
      #pragma unroll
      for (int kk = 0; kk < 2; ++kk) {
        const int kb = kk*64 + ((lane>>4)<<4);
        v8s a[2], bfr[4];
        #pragma unroll
        for (int i = 0; i < 2; ++i) {
          int mr = wv*32 + i*16 + (lane & 15);
          a[i] = *(const v8s*)(wb + mr*128 + (kb ^ ((mr & 7) << 4)));
        }
        #pragma unroll
        for (int j = 0; j < 4; ++j) {
          int nr = j*16 + (lane & 15);
          bfr[j] = *(const v8s*)(lds + nr*512 + kt*128 + (kb ^ ((nr & 7) << 4)));
        }
        #pragma unroll
        for (int i = 0; i < 2; ++i)
          #pragma unroll
          for (int j = 0; j < 4; ++j)
            acc[i][j] = __builtin_amdgcn_mfma_f32_16x16x32_bf16(a[i], bfr[j], acc[i][j], 0, 0, 0);
      }
      __builtin_amdgcn_s_setprio(0);
    }
    if (s < 23) {
      if (s == 20 || s == 21)                       asm volatile("s_waitcnt vmcnt(36)" ::: "memory");
      else if (s == 22)                             asm volatile("s_waitcnt vmcnt(0)"  ::: "memory");
      else if (s==4||s==5||s==8||s==9||s==12||s==13||s==16||s==17)
                                                    asm volatile("s_waitcnt vmcnt(12)" ::: "memory");
      else                                          asm volatile("s_waitcnt vmcnt(4)"  ::: "memory");
      __builtin_amdgcn_s_barrier();
      __builtin_amdgcn_sched_barrier(0);
    }
  }
  epilogue(5, accB);
}

// ---------------- reducer: part[b][h][c][wr] -> xmean[b][c][r] (coalesced) ----
__global__ __launch_bounds__(256) void k_xmr(const float* __restrict__ part,
                                             float* __restrict__ xmean) {
  const int blk = blockIdx.x;              // 512: b(3) | rh(3) | item(3)
  const int item = blk & 7;
  const int b = blk >> 6, rh = (blk >> 3) & 7;
  const int t = threadIdx.x;
  const int flat = item*256 + t;
  float acc = 0.f;
  const float* pp = part + (size_t)(b*64 + rh*8)*2048 + flat;
  #pragma unroll
  for (int j = 0; j < 8; ++j) acc += pp[(size_t)j*2048];
  const int c = flat >> 3, wc = flat & 7;
  xmean[(size_t)((b*256 + c) << 6) + (rh << 3) + wc] = acc * 0.015625f;
}

// ---------------- routing: fp32 region GEMM + top-4 ---------------------------
__global__ __launch_bounds__(256) void k_route(const float* __restrict__ xmean,
                                               const float* __restrict__ w_qkv,
                                               const float* __restrict__ b_qkv,
                                               int* __restrict__ topk) {
  __shared__ float xm[128][64];
  __shared__ float qr[64][33];
  __shared__ float kr[64][33];
  const int bh = blockIdx.x, b = bh >> 3, head = bh & 7;
  const int tid = threadIdx.x;
  const int d = tid & 31, r0 = tid >> 5;
  float qacc[8], kacc[8];
  const float bq = b_qkv[head*32 + d], bk = b_qkv[256 + head*32 + d];
  #pragma unroll
  for (int i = 0; i < 8; ++i) { qacc[i] = bq; kacc[i] = bk; }

  for (int c0 = 0; c0 < 256; c0 += 128) {
    __syncthreads();
    #pragma unroll
    for (int i = 0; i < 32; ++i) {
      int idx = i*256 + tid;
      int row = idx >> 6, col = idx & 63;
      xm[row][col] = xmean[(size_t)(b*256 + c0 + row)*64 + col];
    }
    __syncthreads();
    const float* wqp = w_qkv + (head*32 + d)*256 + c0;
    const float* wkp = w_qkv + (256 + head*32 + d)*256 + c0;
    for (int c = 0; c < 128; ++c) {
      float wq = wqp[c], wk = wkp[c];
      #pragma unroll
      for (int i = 0; i < 8; ++i) {
        float xv = xm[c][r0 + 8*i];
        qacc[i] += wq * xv;
        kacc[i] += wk * xv;
      }
    }
  }
  #pragma unroll
  for (int i = 0; i < 8; ++i) { qr[r0+8*i][d] = qacc[i]; kr[r0+8*i][d] = kacc[i]; }
  __syncthreads();

  float* ar = &xm[0][0];
  for (int item = tid; item < 4096; item += 256) {
    int i = item >> 6, j = item & 63;
    float s = 0.f;
    #pragma unroll
    for (int dd = 0; dd < 32; ++dd) s += qr[i][dd]*kr[j][dd];
    ar[i*64 + j] = s;
  }
  __syncthreads();
  if (tid < 64) {
    for (int kk = 0; kk < 4; ++kk) {
      float best = -3e38f; int bj = 0;
      for (int j = 0; j < 64; ++j) {
        float v = ar[tid*64 + j];
        if (v > best) { best = v; bj = j; }
      }
      ar[tid*64 + bj] = -3e38f;
      topk[(bh*64 + tid)*4 + kk] = bj;
    }
  }
}

// ---------------- proj GEMM (M256 x N64, BK=64, double-buffered, setprio) -----
__global__ __launch_bounds__(256) void k_proj(
    const unsigned short* __restrict__ Wp,
    const unsigned short* __restrict__ Bmat,
    const float* __restrict__ bias,
    float* __restrict__ outp) {
  __shared__ __align__(16) char lds[81920];   // W0 32K | W1 32K | X0 8K | X1 8K
  const int tid = threadIdx.x;
  const int wv = tid >> 6, lane = tid & 63;
  const int nt = blockIdx.x;

  v4f acc[4][4];
  #pragma unroll
  for (int i = 0; i < 4; ++i)
    #pragma unroll
    for (int j = 0; j < 4; ++j) acc[i][j] = (v4f){0.f,0.f,0.f,0.f};

  const char* wlanebase = (const char*)Wp + ((size_t)(lane>>3))*512 + (lane&7)*16;
  const size_t prowlane = (size_t)(nt*64 + (lane>>3))*512 + (lane&7)*16;

  {
    #pragma unroll
    for (int o = 0; o < 8; ++o) {
      int op = wv*8 + o;
      g2l16(wlanebase + (size_t)(op*8)*512, lds + op*1024);
    }
    #pragma unroll
    for (int o = 0; o < 2; ++o) {
      int op = wv*2 + o;
      g2l16((const char*)Bmat + prowlane + (size_t)(op*8)*512, lds + 65536 + op*1024);
    }
    asm volatile("s_waitcnt vmcnt(0)" ::: "memory");
    __syncthreads();
  }

  #pragma unroll
  for (int kt = 0; kt < 4; ++kt) {
    const int cur = kt & 1;
    if (kt < 3) {
      const int k0b = (kt + 1)*128;
      char* wb = lds + (cur^1)*32768;
      char* xb = lds + 65536 + (cur^1)*8192;
      #pragma unroll
      for (int o = 0; o < 8; ++o) {
        int op = wv*8 + o;
        g2l16(wlanebase + (size_t)(op*8)*512 + k0b, wb + op*1024);
      }
      #pragma unroll
      for (int o = 0; o < 2; ++o) {
        int op = wv*2 + o;
        g2l16((const char*)Bmat + prowlane + (size_t)(op*8)*512 + k0b, xb + op*1024);
      }
    }
    const char* wb = lds + cur*32768;
    const char* xb = lds + 65536 + cur*8192;
    __builtin_amdgcn_s_setprio(1);
    #pragma unroll
    for (int kk = 0; kk < 2; ++kk) {
      const int kb = kk*64 + ((lane>>4)<<4);
      v8s a[4], b[4];
      #pragma unroll
      for (int i = 0; i < 4; ++i) {
        int mr = wv*64 + i*16 + (lane & 15);
        a[i] = *(const v8s*)(wb + mr*128 + (kb ^ ((mr & 7) << 4)));
      }
      #pragma unroll
      for (int j = 0; j < 4; ++j) {
        int nr = j*16 + (lane & 15);
        b[j] = *(const v8s*)(xb + nr*128 + (kb ^ ((nr & 7) << 4)));
      }
      #pragma unroll
      for (int i = 0; i < 4; ++i)
        #pragma unroll
        for (int j = 0; j < 4; ++j)
          acc[i][j] = __builtin_amdgcn_mfma_f32_16x16x32_bf16(a[i], b[j], acc[i][j], 0, 0, 0);
    }
    __builtin_amdgcn_s_setprio(0);
    if (kt < 3) {
      asm volatile("s_waitcnt vmcnt(0)" ::: "memory");
      __syncthreads();
    }
  }

  #pragma unroll
  for (int i = 0; i < 4; ++i) {
    int o = wv*64 + i*16 + ((lane >> 4) << 2);
    float b0 = bias[o], b1 = bias[o+1], b2 = bias[o+2], b3 = bias[o+3];
    #pragma unroll
    for (int j = 0; j < 4; ++j) {
      int p = nt*64 + j*16 + (lane & 15);
      int bb = p >> 12, ploc = p & 4095;
      float* dst = outp + ((size_t)(bb*256 + o))*4096 + ploc;
      dst[0]     = acc[i][j][0] + b0;
      dst[4096]  = acc[i][j][1] + b1;
      dst[8192]  = acc[i][j][2] + b2;
      dst[12288] = acc[i][j][3] + b3;
    }
  }
}

// ---------------- MFMA token attention: 1 wave per (bh, region), no LDS -------
__global__ __launch_bounds__(256) void k_attn(const unsigned short* __restrict__ qw,
                                              const unsigned short* __restrict__ kw,
                                              const unsigned short* __restrict__ vwt,
                                              const int* __restrict__ topk,
                                              unsigned short* __restrict__ owt) {
  const int lane = threadIdx.x & 63;
  const int W = blockIdx.x*4 + (threadIdx.x >> 6);
  const int bh = W >> 6, rr = W & 63;
  const int lo5 = lane & 31, hi = lane >> 5;
  const int b = bh >> 3, head = bh & 7;

  const unsigned short* qb = qw + (size_t)(bh*64 + rr)*2048;
  v8s qf[2][2];
  #pragma unroll
  for (int qt = 0; qt < 2; ++qt)
    #pragma unroll
    for (int ck = 0; ck < 2; ++ck)
      qf[qt][ck] = *(const v8s*)(qb + (qt*32 + lo5)*32 + ck*16 + hi*8);

  int idx4[4];
  #pragma unroll
  for (int w = 0; w < 4; ++w) idx4[w] = topk[(bh*64 + rr)*4 + w];

  v16f O[2];
  #pragma unroll
  for (int qt = 0; qt < 2; ++qt)
    #pragma unroll
    for (int r = 0; r < 16; ++r) O[qt][r] = 0.f;
  float lsum[2] = {0.f, 0.f};

  #pragma unroll
  for (int w = 0; w < 4; ++w) {
    const unsigned short* kb = kw  + (size_t)(bh*64 + idx4[w])*2048;
    const unsigned short* vb = vwt + (size_t)(bh*64 + idx4[w])*2048;
    v8s kf[2][2], vf[4];
    #pragma unroll
    for (int kt = 0; kt < 2; ++kt)
      #pragma unroll
      for (int ck = 0; ck < 2; ++ck)
        kf[kt][ck] = *(const v8s*)(kb + (kt*32 + lo5)*32 + ck*16 + hi*8);
    #pragma unroll
    for (int mk = 0; mk < 4; ++mk)                 // re-blocked v layout read
      vf[mk] = *(const v8s*)(vb + (mk*2 + hi)*256 + lo5*8);

    v16f S[2][2];
    __builtin_amdgcn_s_setprio(1);
    #pragma unroll
    for (int kt = 0; kt < 2; ++kt)
      #pragma unroll
      for (int qt = 0; qt < 2; ++qt) {
        v16f z;
        #pragma unroll
        for (int r = 0; r < 16; ++r) z[r] = 0.f;
        z = __builtin_amdgcn_mfma_f32_32x32x16_bf16(kf[kt][0], qf[qt][0], z, 0, 0, 0);
        S[kt][qt] = __builtin_amdgcn_mfma_f32_32x32x16_bf16(kf[kt][1], qf[qt][1], z, 0, 0, 0);
      }
    __builtin_amdgcn_s_setprio(0);

    #pragma unroll
    for (int kt = 0; kt < 2; ++kt) {
      #pragma unroll
      for (int qt = 0; qt < 2; ++qt) {
        float p[16];
        #pragma unroll
        for (int r = 0; r < 16; ++r)
          p[r] = __builtin_amdgcn_exp2f(__builtin_fmaf(S[kt][qt][r], EXP_C1, -EXP_C2));
        float s01 = (p[0]+p[1]) + (p[2]+p[3]);
        float s23 = (p[4]+p[5]) + (p[6]+p[7]);
        float s45 = (p[8]+p[9]) + (p[10]+p[11]);
        float s67 = (p[12]+p[13]) + (p[14]+p[15]);
        lsum[qt] += (s01 + s23) + (s45 + s67);

        unsigned wh[8], wl[8];
        #pragma unroll
        for (int i = 0; i < 8; ++i) {
          wh[i] = cvtpk(p[2*i], p[2*i+1]);
          float l0 = p[2*i]   - bflo(wh[i]);
          float l1 = p[2*i+1] - bfhi(wh[i]);
          wl[i] = cvtpk(l0, l1);
        }
        pl32swap(wh[0], wh[2]); pl32swap(wh[1], wh[3]);
        pl32swap(wh[4], wh[6]); pl32swap(wh[5], wh[7]);
        pl32swap(wl[0], wl[2]); pl32swap(wl[1], wl[3]);
        pl32swap(wl[4], wl[6]); pl32swap(wl[5], wl[7]);
        union { unsigned u[4]; v8s v; } fA, fB;
        fA.u[0] = wh[0]; fA.u[1] = wh[1]; fA.u[2] = wh[2]; fA.u[3] = wh[3];
        fB.u[0] = wl[0]; fB.u[1] = wl[1]; fB.u[2] = wl[2]; fB.u[3] = wl[3];
        __builtin_amdgcn_s_setprio(1);
        O[qt] = __builtin_amdgcn_mfma_f32_32x32x16_bf16(fA.v, vf[2*kt], O[qt], 0, 0, 0);
        O[qt] = __builtin_amdgcn_mfma_f32_32x32x16_bf16(fB.v, vf[2*kt], O[qt], 0, 0, 0);
        __builtin_amdgcn_s_setprio(0);
        fA.u[0] = wh[4]; fA.u[1] = wh[5]; fA.u[2] = wh[6]; fA.u[3] = wh[7];
        fB.u[0] = wl[4]; fB.u[1] = wl[5]; fB.u[2] = wl[6]; fB.u[7 - 7] = wl[4]; // no-op guard
        fB.u[0] = wl[4]; fB.u[1] = wl[5]; fB.u[2] = wl[6]; fB.u[3] = wl[7];
        __builtin_amdgcn_s_setprio(1);
        O[qt] = __builtin_amdgcn_mfma_f32_32x32x16_bf16(fA.v, vf[2*kt+1], O[qt], 0, 0, 0);
        O[qt] = __builtin_amdgcn_mfma_f32_32x32x16_bf16(fB.v, vf[2*kt+1], O[qt], 0, 0, 0);
        __builtin_amdgcn_s_setprio(0);
      }
    }
  }

  float linv[2];
  #pragma unroll
  for (int qt = 0; qt < 2; ++qt) {
    float t = lsum[qt] + __shfl_xor(lsum[qt], 32);
    linv[qt] = 1.0f / t;
  }

  #pragma unroll
  for (int qt = 0; qt < 2; ++qt) {
    #pragma unroll
    for (int r = 0; r < 16; ++r) {
      int q = (r & 3) + 8*(r >> 2) + 4*hi;
      float li = __shfl(linv[qt], q);
      float val = O[qt][r] * li;
      int tok = qt*32 + q;
      int h = ((rr >> 3) << 3) | (tok >> 3);
      int wcol = ((rr & 7) << 3) | (tok & 7);
      int pg = (b << 12) | (h << 6) | wcol;
      int col = ((head >> 1) << 6) | ((((head & 1) << 5) + lo5) ^ ((tok & 7) << 3));
      owt[(size_t)pg*256 + col] = bf16r(val);
    }
  }
}

extern "C" void kernel_launch(void* const* d_in, const int* in_sizes, int n_in,
                              void* d_out, int out_size, void* d_ws, size_t ws_size,
                              hipStream_t stream) {
  (void)in_sizes; (void)n_in; (void)out_size; (void)ws_size;
  const float* x      = (const float*)d_in[0];
  const float* w_qkv  = (const float*)d_in[1];
  const float* b_qkv  = (const float*)d_in[2];
  const float* w_proj = (const float*)d_in[3];
  const float* b_proj = (const float*)d_in[4];
  float* out = (float*)d_out;

  char* ws = (char*)d_ws;
  unsigned short* owt = (unsigned short*)ws;                   // 16.78 MB
  unsigned short* Wq  = (unsigned short*)(ws + 16777216);      // 0.39 MB
  unsigned short* Wp  = (unsigned short*)(ws + 17170432);      // 0.13 MB
  unsigned short* qw  = (unsigned short*)(ws + 17301504);      // 16.78 MB
  unsigned short* kw  = (unsigned short*)(ws + 34078720);      // 16.78 MB
  unsigned short* vwt = (unsigned short*)(ws + 50855936);      // 16.78 MB (re-blocked)
  float* part         = (float*)(ws + 67633152);               // 4.19 MB [b][h][c][wr]
  float* xmean        = (float*)(ws + 71827456);               // 0.52 MB [b][c][r]
  int* topk           = (int*)(ws + 72351744);                 // 64 KB

  k_wprep<<<dim3(1024), 256, 0, stream>>>(w_qkv, w_proj, Wq, Wp);
  k_fqkv <<<dim3(512),  256, 0, stream>>>(x, Wq, b_qkv, qw, kw, vwt, part);
  k_xmr  <<<dim3(512),  256, 0, stream>>>(part, xmean);
  k_route<<<dim3(64),   256, 0, stream>>>(xmean, w_qkv, b_qkv, topk);
  k_attn <<<dim3(1024), 256, 0, stream>>>(qw, kw, vwt, topk, owt);
  k_proj <<<dim3(512),  256, 0, stream>>>(Wp, owt, b_proj, out);
}

// Round 20
// 112.767 us; speedup vs baseline: 1.0174x; 1.0174x over previous
//
#include <hip/hip_runtime.h>
#include <hip/hip_bf16.h>

// B=8, DIM=256, HEADS=8, HD=32, WS=8, TOPK=4, H=W=64, gh=gw=8, R=64, T=64, BH=64.
#define ATT_SCALE 0.17677669529663687f
#define EXP_C1 0.2550349235534668f        // ATT_SCALE * log2(e)
#define EXP_C2 23.083120654223400f        // 16 * log2(e)

typedef short v8s __attribute__((ext_vector_type(8)));
typedef float v4f __attribute__((ext_vector_type(4)));
typedef float v16f __attribute__((ext_vector_type(16)));
typedef const __attribute__((address_space(1))) unsigned int gu32;
typedef __attribute__((address_space(3))) unsigned int lu32;

__device__ __forceinline__ void g2l16(const void* g, void* l) {
  __builtin_amdgcn_global_load_lds((gu32*)g, (lu32*)l, 16, 0, 0);
}

__device__ __forceinline__ float bflo(unsigned u){ union{unsigned i;float f;}x; x.i=u<<16; return x.f; }
__device__ __forceinline__ float bfhi(unsigned u){ union{unsigned i;float f;}x; x.i=u&0xffff0000u; return x.f; }
__device__ __forceinline__ unsigned short bf16r(float v){
  __hip_bfloat16 h = __float2bfloat16(v);
  return *reinterpret_cast<unsigned short*>(&h);
}
__device__ __forceinline__ unsigned pack_bf2(float a, float b){
  return (unsigned)bf16r(a) | ((unsigned)bf16r(b) << 16);
}
__device__ __forceinline__ unsigned cvtpk(float lo, float hi){
  unsigned r;
  asm("v_cvt_pk_bf16_f32 %0, %1, %2" : "=v"(r) : "v"(lo), "v"(hi));
  return r;
}
__device__ __forceinline__ void pl32swap(unsigned &a, unsigned &b){
  asm volatile("v_permlane32_swap_b32 %0, %1" : "+v"(a), "+v"(b));
}

// ---------------- W prep: fp32 -> bf16, K-swizzled -----------------------------
__global__ __launch_bounds__(256) void k_wprep(const float* __restrict__ w_qkv,
                                               const float* __restrict__ w_proj,
                                               unsigned short* __restrict__ Wq,
                                               unsigned short* __restrict__ Wp) {
  const int m = blockIdx.x, t = threadIdx.x;
  const float* src = (m < 768) ? (w_qkv + m*256) : (w_proj + (size_t)(m - 768)*256);
  unsigned short* dst = (m < 768) ? (Wq + m*256) : (Wp + (size_t)(m - 768)*256);
  int col = (t & ~63) | ((t & 63) ^ ((m & 7) << 3));   // (m-768)&7 == m&7
  dst[col] = bf16r(src[t]);
}

// ---------------- FUSED: x transpose->LDS + window partials + qkv MFMA GEMM ----
// Phase 2: 24-stage pipeline, W TRIPLE-buffered, counted vmcnt + RAW s_barrier.
// v layout re-blocked to [BH][R][t>>3][HD][t&7]: full-sector coalesced writes.
__global__ __launch_bounds__(256) void k_fqkv(
    const float* __restrict__ x,
    const unsigned short* __restrict__ Wq,
    const float* __restrict__ bias,
    unsigned short* __restrict__ qbuf, unsigned short* __restrict__ kbuf,
    unsigned short* __restrict__ vbuf, float* __restrict__ part) {
  __shared__ __align__(16) char lds[81920];  // [0,32K) X | 3 x 16K W bufs
  const int tid = threadIdx.x;
  const int wv = tid >> 6, lane = tid & 63;
  const int nt = blockIdx.x;
  const int b = nt >> 6, pc = nt & 63;
  const int p0 = pc << 6;
  float* pbuf = (float*)(lds + 65536);       // 8 KB overlay on W buf2 (dead until s=0)

  const char* wlanebase = (const char*)Wq + ((size_t)(lane >> 3))*512 + (lane & 7)*16;

  auto stage = [&](int s2, int buf) {
    const int m2 = s2 >> 2, kt2 = s2 & 3;
    char* dst = lds + 32768 + buf*16384;
    #pragma unroll
    for (int o = 0; o < 4; ++o) {
      int op = wv*4 + o;
      g2l16(wlanebase + (size_t)(m2*128 + op*8)*512 + kt2*128, dst + op*1024);
    }
  };

  // prologue W stages issued FIRST: their L2 latency hides under phase 1
  stage(0, 0);
  stage(1, 1);

  // ---- phase 1: transpose + partials
  #pragma unroll
  for (int cc = 0; cc < 4; ++cc) {
    float hi[16];
    const float* xp = x + ((size_t)(b*256 + cc*64 + wv*16))*4096 + p0 + lane;
    #pragma unroll
    for (int i = 0; i < 16; ++i) hi[i] = xp[(size_t)i*4096];

    #pragma unroll
    for (int i = 0; i < 16; ++i) {
      float s = hi[i];
      s += __shfl_xor(s, 1);
      s += __shfl_xor(s, 2);
      s += __shfl_xor(s, 4);
      if ((lane & 7) == 0) pbuf[cc*512 + (wv*16 + i)*8 + (lane >> 3)] = s;
    }
    #pragma unroll
    for (int gi = 0; gi < 2; ++gi) {
      uint4 uh;
      uh.x = pack_bf2(hi[gi*8+0], hi[gi*8+1]); uh.y = pack_bf2(hi[gi*8+2], hi[gi*8+3]);
      uh.z = pack_bf2(hi[gi*8+4], hi[gi*8+5]); uh.w = pack_bf2(hi[gi*8+6], hi[gi*8+7]);
      int off = lane*512 + cc*128 + ((wv*32 + gi*16) ^ ((lane & 7) << 4));
      *(uint4*)(lds + off) = uh;
    }
  }
  __syncthreads();
  {
    const size_t pbase = (size_t)(b*64 + pc)*2048;
    #pragma unroll
    for (int s = 0; s < 8; ++s) part[pbase + s*256 + tid] = pbuf[s*256 + tid];
  }
  __syncthreads();   // drains vmcnt -> prologue stages 0,1 landed; pbuf dead

  auto epilogue = [&](int mm, v4f (*acc)[4]) {
    if (mm < 4) {                             // q (mm 0,1) / k (mm 2,3)
      unsigned short* outbuf = (mm < 2) ? qbuf : kbuf;
      #pragma unroll
      for (int i = 0; i < 2; ++i) {
        int o = mm*128 + wv*32 + i*16 + ((lane >> 4) << 2);
        int head = (o >> 5) & 7, d0 = o & 31;
        float b0 = bias[o], b1 = bias[o+1], b2 = bias[o+2], b3 = bias[o+3];
        #pragma unroll
        for (int j = 0; j < 4; ++j) {
          int p = nt*64 + j*16 + (lane & 15);
          int bb = p >> 12, ploc = p & 4095;
          int h = ploc >> 6, w = ploc & 63;
          int rr = ((h >> 3) << 3) | (w >> 3), tt = ((h & 7) << 3) | (w & 7);
          int bh = bb*8 + head;
          uint2 u;
          u.x = pack_bf2(acc[i][j][0] + b0, acc[i][j][1] + b1);
          u.y = pack_bf2(acc[i][j][2] + b2, acc[i][j][3] + b3);
          *(uint2*)(outbuf + (size_t)(((bh << 6) | rr)*64 + tt)*32 + d0) = u;
        }
      }
    } else {              // v -> re-blocked [BH][R][t>>3][HD 32][t&7]
      #pragma unroll
      for (int i = 0; i < 2; ++i) {
        int o = mm*128 + wv*32 + i*16 + ((lane >> 4) << 2);
        int vch = o - 512;
        int head = vch >> 5, d0 = vch & 31;
        float bv[4] = {bias[o], bias[o+1], bias[o+2], bias[o+3]};
        #pragma unroll
        for (int j = 0; j < 4; ++j) {
          int p = nt*64 + j*16 + (lane & 15);
          int bb = p >> 12, ploc = p & 4095;
          int h = ploc >> 6, w = ploc & 63;
          int rr = ((h >> 3) << 3) | (w >> 3), tt = ((h & 7) << 3) | (w & 7);
          int bh = bb*8 + head;
          size_t base = ((size_t)(((bh << 6) | rr)*8 + (tt >> 3)))*256
                      + (size_t)d0*8 + (tt & 7);
          #pragma unroll
          for (int c = 0; c < 4; ++c)
            vbuf[base + (size_t)c*8] = bf16r(acc[i][j][c] + bv[c]);
        }
      }
    }
  };

  v4f accA[2][4], accB[2][4];

  #pragma unroll
  for (int s = 0; s < 24; ++s) {
    const int m = s >> 2, kt = s & 3, cur = s % 3;
    v4f (*acc)[4] = (m & 1) ? accB : accA;
    if (kt == 0) {
      #pragma unroll
      for (int i = 0; i < 2; ++i)
        #pragma unroll
        for (int j = 0; j < 4; ++j) acc[i][j] = (v4f){0.f,0.f,0.f,0.f};
    }
    if (s < 22) stage(s + 2, (s + 2) % 3);
    if (kt == 0 && m > 0) {
      __builtin_amdgcn_sched_barrier(0);      // keep stores AFTER the stage loads
      epilogue(m - 1, (m & 1) ? accA : accB);
      __builtin_amdgcn_sched_barrier(0);
    }
    {
      const char* wb = lds + 32768 + cur*16384;
      __builtin_amdgcn_s_setprio(1);
      #pragma unroll
      for (int kk = 0; kk < 2; ++kk) {
        const int kb = kk*64 + ((lane>>4)<<4);
        v8s a[2], bfr[4];
        #pragma unroll
        for (int i = 0; i < 2; ++i) {
          int mr = wv*32 + i*16 + (lane & 15);
          a[i] = *(const v8s*)(wb + mr*128 + (kb ^ ((mr & 7) << 4)));
        }
        #pragma unroll
        for (int j = 0; j < 4; ++j) {
          int nr = j*16 + (lane & 15);
          bfr[j] = *(const v8s*)(lds + nr*512 + kt*128 + (kb ^ ((nr & 7) << 4)));
        }
        #pragma unroll
        for (int i = 0; i < 2; ++i)
          #pragma unroll
          for (int j = 0; j < 4; ++j)
            acc[i][j] = __builtin_amdgcn_mfma_f32_16x16x32_bf16(a[i], bfr[j], acc[i][j], 0, 0, 0);
      }
      __builtin_amdgcn_s_setprio(0);
    }
    if (s < 23) {
      if (s == 20 || s == 21)                       asm volatile("s_waitcnt vmcnt(36)" ::: "memory");
      else if (s == 22)                             asm volatile("s_waitcnt vmcnt(0)"  ::: "memory");
      else if (s==4||s==5||s==8||s==9||s==12||s==13||s==16||s==17)
                                                    asm volatile("s_waitcnt vmcnt(12)" ::: "memory");
      else                                          asm volatile("s_waitcnt vmcnt(4)"  ::: "memory");
      __builtin_amdgcn_s_barrier();
      __builtin_amdgcn_sched_barrier(0);
    }
  }
  epilogue(5, accB);
}

// ---------------- reducer: part[b][h][c][wr] -> xmean[b][c][r] (coalesced) ----
__global__ __launch_bounds__(256) void k_xmr(const float* __restrict__ part,
                                             float* __restrict__ xmean) {
  const int blk = blockIdx.x;              // 512: b(3) | rh(3) | item(3)
  const int item = blk & 7;
  const int b = blk >> 6, rh = (blk >> 3) & 7;
  const int t = threadIdx.x;
  const int flat = item*256 + t;
  float acc = 0.f;
  const float* pp = part + (size_t)(b*64 + rh*8)*2048 + flat;
  #pragma unroll
  for (int j = 0; j < 8; ++j) acc += pp[(size_t)j*2048];
  const int c = flat >> 3, wc = flat & 7;
  xmean[(size_t)((b*256 + c) << 6) + (rh << 3) + wc] = acc * 0.015625f;
}

// ---------------- routing: fp32 region GEMM + top-4 ---------------------------
__global__ __launch_bounds__(256) void k_route(const float* __restrict__ xmean,
                                               const float* __restrict__ w_qkv,
                                               const float* __restrict__ b_qkv,
                                               int* __restrict__ topk) {
  __shared__ float xm[128][64];
  __shared__ float qr[64][33];
  __shared__ float kr[64][33];
  const int bh = blockIdx.x, b = bh >> 3, head = bh & 7;
  const int tid = threadIdx.x;
  const int d = tid & 31, r0 = tid >> 5;
  float qacc[8], kacc[8];
  const float bq = b_qkv[head*32 + d], bk = b_qkv[256 + head*32 + d];
  #pragma unroll
  for (int i = 0; i < 8; ++i) { qacc[i] = bq; kacc[i] = bk; }

  for (int c0 = 0; c0 < 256; c0 += 128) {
    __syncthreads();
    #pragma unroll
    for (int i = 0; i < 32; ++i) {
      int idx = i*256 + tid;
      int row = idx >> 6, col = idx & 63;
      xm[row][col] = xmean[(size_t)(b*256 + c0 + row)*64 + col];
    }
    __syncthreads();
    const float* wqp = w_qkv + (head*32 + d)*256 + c0;
    const float* wkp = w_qkv + (256 + head*32 + d)*256 + c0;
    for (int c = 0; c < 128; ++c) {
      float wq = wqp[c], wk = wkp[c];
      #pragma unroll
      for (int i = 0; i < 8; ++i) {
        float xv = xm[c][r0 + 8*i];
        qacc[i] += wq * xv;
        kacc[i] += wk * xv;
      }
    }
  }
  #pragma unroll
  for (int i = 0; i < 8; ++i) { qr[r0+8*i][d] = qacc[i]; kr[r0+8*i][d] = kacc[i]; }
  __syncthreads();

  float* ar = &xm[0][0];
  for (int item = tid; item < 4096; item += 256) {
    int i = item >> 6, j = item & 63;
    float s = 0.f;
    #pragma unroll
    for (int dd = 0; dd < 32; ++dd) s += qr[i][dd]*kr[j][dd];
    ar[i*64 + j] = s;
  }
  __syncthreads();
  if (tid < 64) {
    for (int kk = 0; kk < 4; ++kk) {
      float best = -3e38f; int bj = 0;
      for (int j = 0; j < 64; ++j) {
        float v = ar[tid*64 + j];
        if (v > best) { best = v; bj = j; }
      }
      ar[tid*64 + bj] = -3e38f;
      topk[(bh*64 + tid)*4 + kk] = bj;
    }
  }
}

// ---------------- proj GEMM (M256 x N64, BK=64, double-buffered, setprio) -----
__global__ __launch_bounds__(256) void k_proj(
    const unsigned short* __restrict__ Wp,
    const unsigned short* __restrict__ Bmat,
    const float* __restrict__ bias,
    float* __restrict__ outp) {
  __shared__ __align__(16) char lds[81920];   // W0 32K | W1 32K | X0 8K | X1 8K
  const int tid = threadIdx.x;
  const int wv = tid >> 6, lane = tid & 63;
  const int nt = blockIdx.x;

  v4f acc[4][4];
  #pragma unroll
  for (int i = 0; i < 4; ++i)
    #pragma unroll
    for (int j = 0; j < 4; ++j) acc[i][j] = (v4f){0.f,0.f,0.f,0.f};

  const char* wlanebase = (const char*)Wp + ((size_t)(lane>>3))*512 + (lane&7)*16;
  const size_t prowlane = (size_t)(nt*64 + (lane>>3))*512 + (lane&7)*16;

  {
    #pragma unroll
    for (int o = 0; o < 8; ++o) {
      int op = wv*8 + o;
      g2l16(wlanebase + (size_t)(op*8)*512, lds + op*1024);
    }
    #pragma unroll
    for (int o = 0; o < 2; ++o) {
      int op = wv*2 + o;
      g2l16((const char*)Bmat + prowlane + (size_t)(op*8)*512, lds + 65536 + op*1024);
    }
    asm volatile("s_waitcnt vmcnt(0)" ::: "memory");
    __syncthreads();
  }

  #pragma unroll
  for (int kt = 0; kt < 4; ++kt) {
    const int cur = kt & 1;
    if (kt < 3) {
      const int k0b = (kt + 1)*128;
      char* wb = lds + (cur^1)*32768;
      char* xb = lds + 65536 + (cur^1)*8192;
      #pragma unroll
      for (int o = 0; o < 8; ++o) {
        int op = wv*8 + o;
        g2l16(wlanebase + (size_t)(op*8)*512 + k0b, wb + op*1024);
      }
      #pragma unroll
      for (int o = 0; o < 2; ++o) {
        int op = wv*2 + o;
        g2l16((const char*)Bmat + prowlane + (size_t)(op*8)*512 + k0b, xb + op*1024);
      }
    }
    const char* wb = lds + cur*32768;
    const char* xb = lds + 65536 + cur*8192;
    __builtin_amdgcn_s_setprio(1);
    #pragma unroll
    for (int kk = 0; kk < 2; ++kk) {
      const int kb = kk*64 + ((lane>>4)<<4);
      v8s a[4], b[4];
      #pragma unroll
      for (int i = 0; i < 4; ++i) {
        int mr = wv*64 + i*16 + (lane & 15);
        a[i] = *(const v8s*)(wb + mr*128 + (kb ^ ((mr & 7) << 4)));
      }
      #pragma unroll
      for (int j = 0; j < 4; ++j) {
        int nr = j*16 + (lane & 15);
        b[j] = *(const v8s*)(xb + nr*128 + (kb ^ ((nr & 7) << 4)));
      }
      #pragma unroll
      for (int i = 0; i < 4; ++i)
        #pragma unroll
        for (int j = 0; j < 4; ++j)
          acc[i][j] = __builtin_amdgcn_mfma_f32_16x16x32_bf16(a[i], b[j], acc[i][j], 0, 0, 0);
    }
    __builtin_amdgcn_s_setprio(0);
    if (kt < 3) {
      asm volatile("s_waitcnt vmcnt(0)" ::: "memory");
      __syncthreads();
    }
  }

  #pragma unroll
  for (int i = 0; i < 4; ++i) {
    int o = wv*64 + i*16 + ((lane >> 4) << 2);
    float b0 = bias[o], b1 = bias[o+1], b2 = bias[o+2], b3 = bias[o+3];
    #pragma unroll
    for (int j = 0; j < 4; ++j) {
      int p = nt*64 + j*16 + (lane & 15);
      int bb = p >> 12, ploc = p & 4095;
      float* dst = outp + ((size_t)(bb*256 + o))*4096 + ploc;
      dst[0]     = acc[i][j][0] + b0;
      dst[4096]  = acc[i][j][1] + b1;
      dst[8192]  = acc[i][j][2] + b2;
      dst[12288] = acc[i][j][3] + b3;
    }
  }
}

// ---------------- MFMA token attention: 1 wave per (bh, region), no LDS -------
__global__ __launch_bounds__(256) void k_attn(const unsigned short* __restrict__ qw,
                                              const unsigned short* __restrict__ kw,
                                              const unsigned short* __restrict__ vwt,
                                              const int* __restrict__ topk,
                                              unsigned short* __restrict__ owt) {
  const int lane = threadIdx.x & 63;
  const int W = blockIdx.x*4 + (threadIdx.x >> 6);
  const int bh = W >> 6, rr = W & 63;
  const int lo5 = lane & 31, hi = lane >> 5;
  const int b = bh >> 3, head = bh & 7;

  const unsigned short* qb = qw + (size_t)(bh*64 + rr)*2048;
  v8s qf[2][2];
  #pragma unroll
  for (int qt = 0; qt < 2; ++qt)
    #pragma unroll
    for (int ck = 0; ck < 2; ++ck)
      qf[qt][ck] = *(const v8s*)(qb + (qt*32 + lo5)*32 + ck*16 + hi*8);

  int idx4[4];
  #pragma unroll
  for (int w = 0; w < 4; ++w) idx4[w] = topk[(bh*64 + rr)*4 + w];

  v16f O[2];
  #pragma unroll
  for (int qt = 0; qt < 2; ++qt)
    #pragma unroll
    for (int r = 0; r < 16; ++r) O[qt][r] = 0.f;
  float lsum[2] = {0.f, 0.f};

  #pragma unroll
  for (int w = 0; w < 4; ++w) {
    const unsigned short* kb = kw  + (size_t)(bh*64 + idx4[w])*2048;
    const unsigned short* vb = vwt + (size_t)(bh*64 + idx4[w])*2048;
    v8s kf[2][2], vf[4];
    #pragma unroll
    for (int kt = 0; kt < 2; ++kt)
      #pragma unroll
      for (int ck = 0; ck < 2; ++ck)
        kf[kt][ck] = *(const v8s*)(kb + (kt*32 + lo5)*32 + ck*16 + hi*8);
    #pragma unroll
    for (int mk = 0; mk < 4; ++mk)                 // re-blocked v layout read
      vf[mk] = *(const v8s*)(vb + (mk*2 + hi)*256 + lo5*8);

    v16f S[2][2];
    __builtin_amdgcn_s_setprio(1);
    #pragma unroll
    for (int kt = 0; kt < 2; ++kt)
      #pragma unroll
      for (int qt = 0; qt < 2; ++qt) {
        v16f z;
        #pragma unroll
        for (int r = 0; r < 16; ++r) z[r] = 0.f;
        z = __builtin_amdgcn_mfma_f32_32x32x16_bf16(kf[kt][0], qf[qt][0], z, 0, 0, 0);
        S[kt][qt] = __builtin_amdgcn_mfma_f32_32x32x16_bf16(kf[kt][1], qf[qt][1], z, 0, 0, 0);
      }
    __builtin_amdgcn_s_setprio(0);

    #pragma unroll
    for (int kt = 0; kt < 2; ++kt) {
      #pragma unroll
      for (int qt = 0; qt < 2; ++qt) {
        float p[16];
        #pragma unroll
        for (int r = 0; r < 16; ++r)
          p[r] = __builtin_amdgcn_exp2f(__builtin_fmaf(S[kt][qt][r], EXP_C1, -EXP_C2));
        float s01 = (p[0]+p[1]) + (p[2]+p[3]);
        float s23 = (p[4]+p[5]) + (p[6]+p[7]);
        float s45 = (p[8]+p[9]) + (p[10]+p[11]);
        float s67 = (p[12]+p[13]) + (p[14]+p[15]);
        lsum[qt] += (s01 + s23) + (s45 + s67);

        unsigned wh[8], wl[8];
        #pragma unroll
        for (int i = 0; i < 8; ++i) {
          wh[i] = cvtpk(p[2*i], p[2*i+1]);
          float l0 = p[2*i]   - bflo(wh[i]);
          float l1 = p[2*i+1] - bfhi(wh[i]);
          wl[i] = cvtpk(l0, l1);
        }
        pl32swap(wh[0], wh[2]); pl32swap(wh[1], wh[3]);
        pl32swap(wh[4], wh[6]); pl32swap(wh[5], wh[7]);
        pl32swap(wl[0], wl[2]); pl32swap(wl[1], wl[3]);
        pl32swap(wl[4], wl[6]); pl32swap(wl[5], wl[7]);
        union { unsigned u[4]; v8s v; } fA, fB;
        fA.u[0] = wh[0]; fA.u[1] = wh[1]; fA.u[2] = wh[2]; fA.u[3] = wh[3];
        fB.u[0] = wl[0]; fB.u[1] = wl[1]; fB.u[2] = wl[2]; fB.u[3] = wl[3];
        __builtin_amdgcn_s_setprio(1);
        O[qt] = __builtin_amdgcn_mfma_f32_32x32x16_bf16(fA.v, vf[2*kt], O[qt], 0, 0, 0);
        O[qt] = __builtin_amdgcn_mfma_f32_32x32x16_bf16(fB.v, vf[2*kt], O[qt], 0, 0, 0);
        __builtin_amdgcn_s_setprio(0);
        fA.u[0] = wh[4]; fA.u[1] = wh[5]; fA.u[2] = wh[6]; fA.u[3] = wh[7];
        fB.u[0] = wl[4]; fB.u[1] = wl[5]; fB.u[2] = wl[6]; fB.u[3] = wl[7];
        __builtin_amdgcn_s_setprio(1);
        O[qt] = __builtin_amdgcn_mfma_f32_32x32x16_bf16(fA.v, vf[2*kt+1], O[qt], 0, 0, 0);
        O[qt] = __builtin_amdgcn_mfma_f32_32x32x16_bf16(fB.v, vf[2*kt+1], O[qt], 0, 0, 0);
        __builtin_amdgcn_s_setprio(0);
      }
    }
  }

  float linv[2];
  #pragma unroll
  for (int qt = 0; qt < 2; ++qt) {
    float t = lsum[qt] + __shfl_xor(lsum[qt], 32);
    linv[qt] = 1.0f / t;
  }

  #pragma unroll
  for (int qt = 0; qt < 2; ++qt) {
    #pragma unroll
    for (int r = 0; r < 16; ++r) {
      int q = (r & 3) + 8*(r >> 2) + 4*hi;
      float li = __shfl(linv[qt], q);
      float val = O[qt][r] * li;
      int tok = qt*32 + q;
      int h = ((rr >> 3) << 3) | (tok >> 3);
      int wcol = ((rr & 7) << 3) | (tok & 7);
      int pg = (b << 12) | (h << 6) | wcol;
      int col = ((head >> 1) << 6) | ((((head & 1) << 5) + lo5) ^ ((tok & 7) << 3));
      owt[(size_t)pg*256 + col] = bf16r(val);
    }
  }
}

extern "C" void kernel_launch(void* const* d_in, const int* in_sizes, int n_in,
                              void* d_out, int out_size, void* d_ws, size_t ws_size,
                              hipStream_t stream) {
  (void)in_sizes; (void)n_in; (void)out_size; (void)ws_size;
  const float* x      = (const float*)d_in[0];
  const float* w_qkv  = (const float*)d_in[1];
  const float* b_qkv  = (const float*)d_in[2];
  const float* w_proj = (const float*)d_in[3];
  const float* b_proj = (const float*)d_in[4];
  float* out = (float*)d_out;

  char* ws = (char*)d_ws;
  unsigned short* owt = (unsigned short*)ws;                   // 16.78 MB
  unsigned short* Wq  = (unsigned short*)(ws + 16777216);      // 0.39 MB
  unsigned short* Wp  = (unsigned short*)(ws + 17170432);      // 0.13 MB
  unsigned short* qw  = (unsigned short*)(ws + 17301504);      // 16.78 MB
  unsigned short* kw  = (unsigned short*)(ws + 34078720);      // 16.78 MB
  unsigned short* vwt = (unsigned short*)(ws + 50855936);      // 16.78 MB (re-blocked)
  float* part         = (float*)(ws + 67633152);               // 4.19 MB [b][h][c][wr]
  float* xmean        = (float*)(ws + 71827456);               // 0.52 MB [b][c][r]
  int* topk           = (int*)(ws + 72351744);                 // 64 KB

  k_wprep<<<dim3(1024), 256, 0, stream>>>(w_qkv, w_proj, Wq, Wp);
  k_fqkv <<<dim3(512),  256, 0, stream>>>(x, Wq, b_qkv, qw, kw, vwt, part);
  k_xmr  <<<dim3(512),  256, 0, stream>>>(part, xmean);
  k_route<<<dim3(64),   256, 0, stream>>>(xmean, w_qkv, b_qkv, topk);
  k_attn <<<dim3(1024), 256, 0, stream>>>(qw, kw, vwt, topk, owt);
  k_proj <<<dim3(512),  256, 0, stream>>>(Wp, owt, b_proj, out);
}